// Round 4
// baseline (904.673 us; speedup 1.0000x reference)
//
#include <hip/hip_runtime.h>

// VQ: B=200000 rows (D=128 fp32) vs K=1024 codes; out = [quant B*D | codes B] fp32.
//
// R6: R5 hit 629us at VALUBusy 81% -- the fp32 VALU wall (pk_fma issue floor
// = 333us). Only the matrix pipe goes faster. Output depends ONLY on argmin
// index, so: fp16 2-way-split MFMA GEMM (dot ~ Xh.Ch + Xh.Cl + Xl.Ch as ONE
// K=384 GEMM; fp16xfp16 products are exact in fp32) + per-row margin bound;
// rows whose best2-best1 margin is below a rigorous error bound get an exact
// recheck (same serial-fma chain as the R2..R5 passing kernels) that
// overwrites codes+quant. Unflagged rows: margin > bound => approx argmin
// provably == exact-chain argmin. xsq is per-row constant => never affects
// argmin => only needed in the recheck.
// Structure: wave owns 16 rows x all 1024 codes. A-frags (Xh,Xl) in regs;
// B-frags streamed from a pre-packed frag-linear fp16 buffer (768KB,
// L2-resident). Zero LDS, zero barriers in the main kernel.
// Layout insurance: A and B frags use the SAME (lane,j)->k convention, so a
// wrong guess of the k permutation cancels (x_m always pairs with c_m).
// C/D mapping col=lane&15,row=(lane>>4)*4+reg is HW-verified.

typedef _Float16 f16;
typedef f16 h8 __attribute__((ext_vector_type(8)));
typedef float f4 __attribute__((ext_vector_type(4)));

#define DDIM 128
#define KCODES 1024

// ---------------- csq (exact 4-chain, unchanged) + zero flag counter --------
__global__ void csq_kernel(const float* __restrict__ cb, float* __restrict__ csq,
                           int* __restrict__ cnt) {
    if (blockIdx.x == 0 && threadIdx.x == 0) *cnt = 0;
    int k = blockIdx.x * blockDim.x + threadIdx.x;
    if (k >= KCODES) return;
    const float* __restrict__ c = cb + (long)k * DDIM;
    float s0 = 0.f, s1 = 0.f, s2 = 0.f, s3 = 0.f;
#pragma unroll
    for (int d = 0; d < DDIM; d += 4) {
        s0 = fmaf(c[d + 0], c[d + 0], s0);
        s1 = fmaf(c[d + 1], c[d + 1], s1);
        s2 = fmaf(c[d + 2], c[d + 2], s2);
        s3 = fmaf(c[d + 3], c[d + 3], s3);
    }
    csq[k] = (s0 + s1) + (s2 + s3);
}

// ---------------- pack B' = [Ch | Cl | Ch] (K=384) frag-linear ---------------
// tile = cb16*12 + kf (cb16: 16-code block 0..63, kf: 32-k frag 0..11).
// Within tile: lane l supplies col = cb16*16 + (l&15), k = kf*32+(l>>4)*8+j.
// Stored as h8 at B2[tile*64 + lane] -> a wave's frag load is 1KB contiguous.
__global__ void bprep_kernel(const float* __restrict__ cb, h8* __restrict__ B2) {
    const int t = blockIdx.x * 256 + threadIdx.x;      // 0..49151
    const int tile = t >> 6;                           // 0..767
    const int lane = t & 63;
    const int cb16 = tile / 12, kf = tile % 12;
    const int col = cb16 * 16 + (lane & 15);
    const int kk0 = kf * 32 + (lane >> 4) * 8;         // 0..376 (one segment)
    const int seg = kk0 >> 7;                          // 0:Ch 1:Cl 2:Ch
    const int kd0 = kk0 & 127;
    const float* __restrict__ p = cb + (long)col * DDIM + kd0;
    h8 out;
#pragma unroll
    for (int j = 0; j < 8; ++j) {
        const float v = p[j];
        const f16 h = (f16)v;
        out[j] = (seg == 1) ? (f16)(v - (float)h) : h;
    }
    B2[tile * 64 + lane] = out;
}

// ---------------- main MFMA kernel: wave = 16 rows x 1024 codes --------------
__launch_bounds__(256)
__global__ void vq_mfma_kernel(const float* __restrict__ x, const float* __restrict__ cb,
                               const h8* __restrict__ B2, const float* __restrict__ csq,
                               float* __restrict__ quant, float* __restrict__ codes,
                               int* __restrict__ cnt, int* __restrict__ list) {
    const int tid = threadIdx.x;
    const int lane = tid & 63;
    const int wv = tid >> 6;
    const long gr0 = (long)blockIdx.x * 64 + (long)wv * 16;  // wave's 16 rows
    const int lr = lane & 15;     // A-row / B-col within a frag
    const int lk = lane >> 4;     // k-group

    // ---- A frags: 16 rows x 128 dims fp32 -> fp16 hi/lo; per-row sumsq ----
    h8 ah[4], al[4];
    float ss = 0.f;
#pragma unroll
    for (int f = 0; f < 4; ++f) {
        const float* p = x + (gr0 + lr) * DDIM + f * 32 + lk * 8;
        const float4 u0 = *(const float4*)p;
        const float4 u1 = *(const float4*)(p + 4);
        const float xv[8] = {u0.x, u0.y, u0.z, u0.w, u1.x, u1.y, u1.z, u1.w};
#pragma unroll
        for (int j = 0; j < 8; ++j) {
            const float v = xv[j];
            const f16 h = (f16)v;
            ah[f][j] = h;
            al[f][j] = (f16)(v - (float)h);
            ss = fmaf(v, v, ss);
        }
    }
    // full-row sumsq (row lr) at every lane: sum the 4 k-groups
    ss += __shfl_xor(ss, 16);
    ss += __shfl_xor(ss, 32);
    // margin threshold: 2*(split+accum err ~3.1e-5*S, S<=sqrt(ss*128)) + fp16
    // denorm-flush slack (<=6.1e-5*sum|c| <= 7.8e-3) + dist-rounding slack.
    const float thr = 2.5e-3f * sqrtf(ss) + 0.04f;

    float b1[4], b2v[4];
    int i1[4];
#pragma unroll
    for (int r = 0; r < 4; ++r) { b1[r] = 3.4e38f; b2v[r] = 3.4e38f; i1[r] = 0; }

#pragma unroll 1
    for (int ct = 0; ct < 8; ++ct) {        // 8 chunks of 128 codes
#pragma unroll 4
        for (int cf = 0; cf < 8; ++cf) {    // 8 col-frags of 16 codes
            const int cb16 = ct * 8 + cf;
            const h8* bp = B2 + cb16 * 12 * 64 + lane;
            f4 acc = (f4){0.f, 0.f, 0.f, 0.f};
#pragma unroll
            for (int kf = 0; kf < 12; ++kf) {
                const h8 bfrag = bp[kf * 64];
                const h8 afrag = (kf < 4) ? ah[kf] : (kf < 8 ? ah[kf - 4] : al[kf - 8]);
                acc = __builtin_amdgcn_mfma_f32_16x16x32_f16(afrag, bfrag, acc, 0, 0, 0);
            }
            // epilogue: score = csq - 2*dot (xsq is a per-row constant ->
            // irrelevant for argmin); track best + second-best, ascending cols
            const int col = ct * 128 + cf * 16 + lr;
            const float cq = csq[col];
#pragma unroll
            for (int r = 0; r < 4; ++r) {
                const float s = fmaf(-2.0f, acc[r], cq);
                if (s < b1[r]) { b2v[r] = b1[r]; b1[r] = s; i1[r] = col; }
                else if (s < b2v[r]) { b2v[r] = s; }
            }
        }
    }

    // ---- reduce (b1,i1,b2) across the 16 lanes of each k-group ----
#pragma unroll
    for (int r = 0; r < 4; ++r) {
#pragma unroll
        for (int off = 1; off <= 8; off <<= 1) {
            const float ob1 = __shfl_xor(b1[r], off);
            const int   oi  = __shfl_xor(i1[r], off);
            const float ob2 = __shfl_xor(b2v[r], off);
            const bool ow = (ob1 < b1[r]) || (ob1 == b1[r] && oi < i1[r]);
            const float nb2 = ow ? fminf(b1[r], ob2) : fminf(ob1, b2v[r]);
            if (ow) { b1[r] = ob1; i1[r] = oi; }
            b2v[r] = nb2;
        }
    }

    // thresholds for the 4 rows this lane-group owns (row = lk*4 + r)
    float thrr[4];
#pragma unroll
    for (int r = 0; r < 4; ++r) thrr[r] = __shfl(thr, lk * 4 + r);

    if (lr == 0) {
#pragma unroll
        for (int r = 0; r < 4; ++r) {
            const long grow = gr0 + lk * 4 + r;
            codes[grow] = (float)i1[r];
            if (!(b2v[r] - b1[r] >= thrr[r])) {   // flag small margin (and NaN)
                const int pos = atomicAdd(cnt, 1);
                list[pos] = (int)grow;
            }
        }
    }

    // ---- gather quant rows: lane handles row m = lane>>2, quarter lane&3 ----
    {
        const int m = lane >> 2;                 // 0..15
        const int src = (m >> 2) * 16;           // first lane of owning group
        const int w0 = __shfl(i1[0], src), w1 = __shfl(i1[1], src);
        const int w2 = __shfl(i1[2], src), w3 = __shfl(i1[3], src);
        const int rs = m & 3;
        const int win = rs == 0 ? w0 : rs == 1 ? w1 : rs == 2 ? w2 : w3;
        const float* __restrict__ crow = cb + (long)win * DDIM + (lane & 3) * 32;
        float* __restrict__ qrow = quant + (gr0 + m) * DDIM + (lane & 3) * 32;
#pragma unroll
        for (int q = 0; q < 8; ++q)
            *(float4*)(qrow + q * 4) = *(const float4*)(crow + q * 4);
    }
}

// ---------------- exact recheck: one wave per flagged row --------------------
// Reproduces the R2/R5 exact chain: dot = single serial fma over d=0..127
// ascending; xsq = 4-chain; dist = fmaf(-2,dot,xsq)+csq; argmin ascending
// index with strict <. Overwrites codes+quant for the row.
__launch_bounds__(256)
__global__ void recheck_kernel(const float* __restrict__ x, const float* __restrict__ cb,
                               const float* __restrict__ csq, float* __restrict__ quant,
                               float* __restrict__ codes, const int* __restrict__ cnt,
                               const int* __restrict__ list) {
    const int n = *cnt;
    const int lane = threadIdx.x & 63;
    const int wid = (blockIdx.x * 256 + threadIdx.x) >> 6;
    const int nw = (gridDim.x * 256) >> 6;
    for (int it = wid; it < n; it += nw) {
        const int row = list[it];
        const float* __restrict__ xr = x + (long)row * DDIM;
        float accv[16];
#pragma unroll
        for (int t = 0; t < 16; ++t) accv[t] = 0.f;
        float s4[4] = {0.f, 0.f, 0.f, 0.f};
#pragma unroll 1
        for (int d0 = 0; d0 < DDIM; d0 += 16) {
            float xv[16];
#pragma unroll
            for (int q = 0; q < 4; ++q) {
                const float4 u = *(const float4*)(xr + d0 + q * 4);
                xv[q * 4 + 0] = u.x; xv[q * 4 + 1] = u.y;
                xv[q * 4 + 2] = u.z; xv[q * 4 + 3] = u.w;
            }
#pragma unroll
            for (int dd = 0; dd < 16; ++dd)
                s4[dd & 3] = fmaf(xv[dd], xv[dd], s4[dd & 3]);
#pragma unroll
            for (int t = 0; t < 16; ++t) {     // full unroll: accv idx constant
                const float* __restrict__ cr = cb + (long)(lane + t * 64) * DDIM + d0;
                float a = accv[t];
#pragma unroll
                for (int q = 0; q < 4; ++q) {
                    const float4 c4 = *(const float4*)(cr + q * 4);
                    a = fmaf(xv[q * 4 + 0], c4.x, a);
                    a = fmaf(xv[q * 4 + 1], c4.y, a);
                    a = fmaf(xv[q * 4 + 2], c4.z, a);
                    a = fmaf(xv[q * 4 + 3], c4.w, a);
                }
                accv[t] = a;
            }
        }
        const float xsq = (s4[0] + s4[1]) + (s4[2] + s4[3]);
        float b = 3.4e38f; int bi = 0;
#pragma unroll
        for (int t = 0; t < 16; ++t) {
            const int k = lane + t * 64;       // ascending per lane
            const float dist = fmaf(-2.0f, accv[t], xsq) + csq[k];
            if (dist < b) { b = dist; bi = k; }
        }
#pragma unroll
        for (int off = 32; off >= 1; off >>= 1) {
            const float ov = __shfl_xor(b, off);
            const int oi = __shfl_xor(bi, off);
            if (ov < b || (ov == b && oi < bi)) { b = ov; bi = oi; }
        }
        if (lane == 0) codes[row] = (float)bi;
        const float* __restrict__ crow = cb + (long)bi * DDIM + lane * 2;
        float* __restrict__ qrow = quant + (long)row * DDIM + lane * 2;
        qrow[0] = crow[0];
        qrow[1] = crow[1];
    }
}

extern "C" void kernel_launch(void* const* d_in, const int* in_sizes, int n_in,
                              void* d_out, int out_size, void* d_ws, size_t ws_size,
                              hipStream_t stream) {
    const float* x  = (const float*)d_in[0];
    const float* cb = (const float*)d_in[1];
    const int B = in_sizes[0] / DDIM;  // 200000

    float* quant = (float*)d_out;
    float* codes = (float*)d_out + (size_t)B * DDIM;

    char* ws = (char*)d_ws;
    float* csq = (float*)ws;                       // 4 KB
    int*   cnt = (int*)(ws + 4096);                // 4 B (+pad)
    h8*    B2  = (h8*)(ws + 8192);                 // 768 KB
    int*   list = (int*)(ws + 8192 + 786432);      // 800 KB

    csq_kernel<<<(KCODES + 255) / 256, 256, 0, stream>>>(cb, csq, cnt);
    bprep_kernel<<<192, 256, 0, stream>>>(cb, B2);
    vq_mfma_kernel<<<B / 64, 256, 0, stream>>>(x, cb, B2, csq, quant, codes, cnt, list);
    recheck_kernel<<<256, 256, 0, stream>>>(x, cb, csq, quant, codes, cnt, list);
}